// Round 7
// baseline (408.492 us; speedup 1.0000x reference)
//
#include <hip/hip_runtime.h>
#include <stdint.h>

// W8A8 int8 GEMM + dequant epilogue, MI355X gfx950.
// R13: the ONE unbenched cell of the guide's regime-gate matrix: T3 (phase
// split) + T4 (counted, aged vmcnt) TOGETHER. R6/R10/R12 = drain0 (41%
// plateau regardless of occupancy 21-38%); R7/R11 = counted vmcnt without
// phases (33-36%). m196/m218: only the combo moves (+28..73%).
// BM=BN=256, BK=128, 512 thr, 8 waves 2Mx4N (wave 128x64, acc 4x2).
// 2-slot LDS 128 KiB. Per K-tile: burst-issue kt+1 (8 loads) at kt top ->
// s_waitcnt vmcnt(8) (kt's loads are 4 phases ~2000cyc aged; never 0 in
// main loop) -> barrier -> 4 phases {6 ds_read; barrier; lgkmcnt(0);
// setprio1; 8 MFMA; setprio0; barrier}. Race-safety: slot[(kt+1)&1]'s last
// reader finished at kt-1's final phase (lgkm0 before its trailing
// barrier); issue is after that barrier in program order.
// BK=128 8-chunk XOR swizzle, measured conflict-free R3/R5/R6/R10/R11/R12.
// out[m,n] = (sum_k A*W + sum_input[m]*zp_w[n]) * si[m]*sw[n] + bias[n]

#define BM 256
#define BN 256
#define BK 128

typedef __attribute__((ext_vector_type(4))) int int32x4;
typedef __attribute__((ext_vector_type(16))) int int32x16;

__device__ __forceinline__ void async_copy16(const uint8_t* g, uint8_t* l) {
  __builtin_amdgcn_global_load_lds(
      (const __attribute__((address_space(1))) uint32_t*)(const void*)g,
      (__attribute__((address_space(3))) uint32_t*)l,
      16, 0, 0);
}

// Coalesced pack, grid-stride: one int32x4 (4 int8-as-int32) -> one uint32.
__global__ __launch_bounds__(256) void pack_kernel(
    const int* __restrict__ A, const int* __restrict__ B,
    uint8_t* __restrict__ A8, uint8_t* __restrict__ B8,
    int nA4, int nTot4) {
  const int stride = gridDim.x * blockDim.x;
  for (int t = blockIdx.x * blockDim.x + threadIdx.x; t < nTot4; t += stride) {
    const int32x4* src;
    uint32_t* dst;
    if (t < nA4) {
      src = (const int32x4*)A + t;
      dst = (uint32_t*)A8 + t;
    } else {
      int u = t - nA4;
      src = (const int32x4*)B + u;
      dst = (uint32_t*)B8 + u;
    }
    int32x4 v = __builtin_nontemporal_load(src);  // read-once stream
    *dst = (uint32_t)(v.x & 255) | ((uint32_t)(v.y & 255) << 8) |
           ((uint32_t)(v.z & 255) << 16) | ((uint32_t)(v.w & 255) << 24);
  }
}

// Stage one 256x128 A tile + 256x128 B tile into one LDS slot (8 issues).
// 512 thr: row_s = tid>>3 (0..63), slot chunk cs = tid&7, global chunk
// cg = cs ^ ((tid>>4)&7); issue p covers rows [p*64, p*64+64).
// Invariant: LDS row r (128 B) slot cs holds global chunk cs ^ ((r>>1)&7).
// Verbatim R10 staging (measured SQ_LDS_BANK_CONFLICT == 0).
__device__ __forceinline__ void stage_tile(
    const uint8_t* Ab, const uint8_t* Bb, size_t sK, int k0,
    uint8_t* AsBuf, uint8_t* BsBuf, int ldst) {
#pragma unroll
  for (int p = 0; p < 4; ++p)
    async_copy16(Ab + (size_t)(p * 64) * sK + k0, AsBuf + p * 8192 + ldst);
#pragma unroll
  for (int p = 0; p < 4; ++p)
    async_copy16(Bb + (size_t)(p * 64) * sK + k0, BsBuf + p * 8192 + ldst);
}

__global__ __launch_bounds__(512, 2) void w8a8_gemm(
    const uint8_t* __restrict__ A8, const uint8_t* __restrict__ B8,
    const float* __restrict__ bias,
    const float* __restrict__ s_in,
    const float* __restrict__ s_w,
    const float* __restrict__ sum_in,
    const int* __restrict__ zp_w,
    float* __restrict__ out,
    int M, int N, int K) {
  __shared__ uint8_t As[2][BM * BK];  // 2 x 32 KiB
  __shared__ uint8_t Bs[2][BN * BK];  // 2 x 32 KiB  -> 128 KiB total

  const int tid = threadIdx.x;
  const int bm = blockIdx.y, bn = blockIdx.x;  // plain 2D grid (best FETCH)
  const int row0 = bm * BM, col0 = bn * BN;

  const int wave = tid >> 6, lane = tid & 63;
  const int m32 = lane & 31, half = lane >> 5;
  const int wm = (wave >> 2) * 128;  // 2 wave-rows of 128
  const int wn = (wave & 3) * 64;    // 4 wave-cols of 64
  const size_t sK = (size_t)K;

  // staging geometry (see stage_tile comment)
  const int row_s = tid >> 3;                   // 0..63
  const int cg = (tid & 7) ^ ((tid >> 4) & 7);
  const int ldst = tid * 16;

  const uint8_t* Ab = A8 + (size_t)(row0 + row_s) * sK + cg * 16;
  const uint8_t* Bb = B8 + (size_t)(col0 + row_s) * sK + cg * 16;

  int32x16 acc[4][2] = {};

  const int NT = K / BK;
  // Prologue: stage K-tile 0 into slot 0.
  stage_tile(Ab, Bb, sK, 0, &As[0][0], &Bs[0][0], ldst);

  const int swzr = (m32 >> 1) & 7;
  for (int kt = 0; kt < NT; ++kt) {
    // Burst-issue kt+1 into the slot last read during kt-1 (race-free:
    // every wave's kt-1 reads retired at lgkm0 before its final barrier).
    if (kt + 1 < NT) {
      stage_tile(Ab, Bb, sK, (kt + 1) * BK, &As[(kt + 1) & 1][0],
                 &Bs[(kt + 1) & 1][0], ldst);
      // kt's 8 loads (issued 4 phases ago) landed; kt+1's 8 stay in flight.
      asm volatile("s_waitcnt vmcnt(8)" ::: "memory");
    } else {
      asm volatile("s_waitcnt vmcnt(0)" ::: "memory");
    }
    __builtin_amdgcn_s_barrier();  // all waves' kt contributions landed

    const uint8_t* Ac = &As[kt & 1][0];
    const uint8_t* Bc = &Bs[kt & 1][0];
#pragma unroll
    for (int ks = 0; ks < 4; ++ks) {
      // --- phase ks: ds-reads for this K-slice ---
      const int gran = ((ks * 2 + half) ^ swzr) * 16;
      int32x4 afrag[4], bfrag[2];
#pragma unroll
      for (int i = 0; i < 4; ++i)
        afrag[i] = *(const int32x4*)&Ac[(wm + i * 32 + m32) * BK + gran];
#pragma unroll
      for (int j = 0; j < 2; ++j)
        bfrag[j] = *(const int32x4*)&Bc[(wn + j * 32 + m32) * BK + gran];
      __builtin_amdgcn_s_barrier();
      asm volatile("s_waitcnt lgkmcnt(0)" ::: "memory");
      __builtin_amdgcn_s_setprio(1);
#pragma unroll
      for (int i = 0; i < 4; ++i)
#pragma unroll
        for (int j = 0; j < 2; ++j)
          acc[i][j] = __builtin_amdgcn_mfma_i32_32x32x32_i8(
              afrag[i], bfrag[j], acc[i][j], 0, 0, 0);
      __builtin_amdgcn_s_setprio(0);
      __builtin_amdgcn_s_barrier();
    }
  }

  // Epilogue: 32x32 C/D layout col=lane&31, row=(reg&3)+8*(reg>>2)+4*(lane>>5).
  float swj[2], zpj[2], bj[2];
#pragma unroll
  for (int j = 0; j < 2; ++j) {
    int gc = col0 + wn + j * 32 + m32;
    swj[j] = s_w[gc];
    zpj[j] = (float)zp_w[gc];
    bj[j] = bias[gc];
  }
#pragma unroll
  for (int i = 0; i < 4; ++i) {
#pragma unroll
    for (int reg = 0; reg < 16; ++reg) {
      int gr = row0 + wm + i * 32 + (reg & 3) + 8 * (reg >> 2) + 4 * half;
      float siv = s_in[gr];
      float suv = sum_in[gr];
      float* orow = out + (size_t)gr * N + col0 + wn + m32;
#pragma unroll
      for (int j = 0; j < 2; ++j) {
        float v = ((float)acc[i][j][reg] + suv * zpj[j]) * (siv * swj[j]) + bj[j];
        __builtin_nontemporal_store(v, &orow[j * 32]);
      }
    }
  }
}

// Fallback (ws too small): unpacked int32 inputs, BK=64, VALU pack + ds_write.
__global__ __launch_bounds__(256) void w8a8_gemm_fallback(
    const int* __restrict__ A32, const int* __restrict__ B32,
    const float* __restrict__ bias,
    const float* __restrict__ s_in,
    const float* __restrict__ s_w,
    const float* __restrict__ sum_in,
    const int* __restrict__ zp_w,
    float* __restrict__ out,
    int M, int N, int K) {
  __shared__ uint8_t As[128 * 64];
  __shared__ uint8_t Bs[128 * 64];
  const int tid = threadIdx.x;
  const int bm = blockIdx.y, bn = blockIdx.x;
  const int row0 = bm * 128, col0 = bn * 128;
  const int wave = tid >> 6, lane = tid & 63;
  const int quad = lane >> 4, r = lane & 15;
  const int wm = (wave >> 1) * 64, wn = (wave & 1) * 64;
  const int lin = tid * 16;
  const int srow = lin >> 6;
  const int scol = lin & 63;
  const size_t sK = (size_t)K;
  int32x4 acc[4][4] = {};
  for (int k0 = 0; k0 < K; k0 += 64) {
#pragma unroll
    for (int c = 0; c < 2; ++c) {
      const int* ag = A32 + (size_t)(row0 + srow + c * 64) * sK + k0 + scol;
      const int* bg = B32 + (size_t)(col0 + srow + c * 64) * sK + k0 + scol;
      int32x4 pa, pb;
#pragma unroll
      for (int q = 0; q < 4; ++q) {
        int4 va = ((const int4*)ag)[q];
        int4 vb = ((const int4*)bg)[q];
        pa[q] = (int)((uint32_t)(va.x & 255) | ((uint32_t)(va.y & 255) << 8) |
                      ((uint32_t)(va.z & 255) << 16) | ((uint32_t)(va.w & 255) << 24));
        pb[q] = (int)((uint32_t)(vb.x & 255) | ((uint32_t)(vb.y & 255) << 8) |
                      ((uint32_t)(vb.z & 255) << 16) | ((uint32_t)(vb.w & 255) << 24));
      }
      *(int32x4*)&As[lin + c * 4096] = pa;
      *(int32x4*)&Bs[lin + c * 4096] = pb;
    }
    __syncthreads();
    int32x4 afrag[4], bfrag[4];
#pragma unroll
    for (int i = 0; i < 4; ++i)
      afrag[i] = *(const int32x4*)&As[(wm + i * 16 + r) * 64 + quad * 16];
#pragma unroll
    for (int j = 0; j < 4; ++j)
      bfrag[j] = *(const int32x4*)&Bs[(wn + j * 16 + r) * 64 + quad * 16];
#pragma unroll
    for (int i = 0; i < 4; ++i)
#pragma unroll
      for (int j = 0; j < 4; ++j)
        acc[i][j] = __builtin_amdgcn_mfma_i32_16x16x64_i8(afrag[i], bfrag[j],
                                                          acc[i][j], 0, 0, 0);
    __syncthreads();
  }
  float swj[4], zpj[4], bj[4];
#pragma unroll
  for (int j = 0; j < 4; ++j) {
    int gc = col0 + wn + j * 16 + r;
    swj[j] = s_w[gc];
    zpj[j] = (float)zp_w[gc];
    bj[j] = bias[gc];
  }
#pragma unroll
  for (int i = 0; i < 4; ++i) {
#pragma unroll
    for (int t = 0; t < 4; ++t) {
      int gr = row0 + wm + i * 16 + quad * 4 + t;
      float siv = s_in[gr];
      float suv = sum_in[gr];
      float* orow = out + (size_t)gr * N + col0 + wn + r;
#pragma unroll
      for (int j = 0; j < 4; ++j) {
        float v = ((float)acc[i][j][t] + suv * zpj[j]) * (siv * swj[j]) + bj[j];
        orow[j * 16] = v;
      }
    }
  }
}

extern "C" void kernel_launch(void* const* d_in, const int* in_sizes, int n_in,
                              void* d_out, int out_size, void* d_ws, size_t ws_size,
                              hipStream_t stream) {
  const int* x_q = (const int*)d_in[0];
  const int* w_q = (const int*)d_in[1];
  const float* bias = (const float*)d_in[2];
  const float* s_in = (const float*)d_in[3];
  const float* s_w = (const float*)d_in[4];
  const float* sum_in = (const float*)d_in[5];
  const int* zp_w = (const int*)d_in[6];
  float* out = (float*)d_out;

  const int M = in_sizes[3];
  const int N = in_sizes[2];
  const int K = in_sizes[0] / M;

  const size_t needA = (size_t)M * K;
  const size_t needB = (size_t)N * K;

  if (ws_size >= needA + needB && (M % BM) == 0 && (N % BN) == 0 &&
      (K % BK) == 0 && (K / BK) >= 2) {
    uint8_t* A8 = (uint8_t*)d_ws;
    uint8_t* B8 = A8 + needA;
    const int nA4 = (int)(needA / 4);
    const int nTot4 = (int)((needA + needB) / 4);
    int nblk = (nTot4 + 255) / 256;
    if (nblk > 2048) nblk = 2048;
    pack_kernel<<<nblk, 256, 0, stream>>>(x_q, w_q, A8, B8, nA4, nTot4);
    dim3 grid(N / BN, M / BM), block(512);
    w8a8_gemm<<<grid, block, 0, stream>>>(A8, B8, bias, s_in, s_w, sum_in,
                                          zp_w, out, M, N, K);
  } else {
    dim3 grid(N / 128, M / 128), block(256);
    w8a8_gemm_fallback<<<grid, block, 0, stream>>>(x_q, w_q, bias, s_in, s_w,
                                                   sum_in, zp_w, out, M, N, K);
  }
}

// Round 8
// 406.378 us; speedup vs baseline: 1.0052x; 1.0052x over previous
//
#include <hip/hip_runtime.h>
#include <stdint.h>

// W8A8 int8 GEMM + dequant epilogue, MI355X gfx950.
// R14: pipe-rebalance round. Budget from measured constants: per
// 256x128 block-K-tile, MFMA = 128 wave-ops x 8.7cyc = 1114 CU-cyc;
// ds_read_b128 = 96 x 12cyc = 1156 CU-cyc -> LDS pipe == MFMA pipe, and
// measured 41% MfmaUtil == the zero-overlap serialization of the two.
// Fix: A has ZERO intra-block reuse (each wave reads its own 64 rows
// once) -> take A off the LDS pipe. Pack A into MFMA-fragment-panel
// order (1-KB coalesced lane-contiguous chunks); GEMM loads A fragments
// direct global->reg (8 dwordx4/thread/K-tile, burst at tile top,
// latency hidden under the B-DMA drain the barrier waits on anyway).
// B keeps R6's verbatim LDS path (4x reuse; swizzle conflict-free,
// 5 rounds measured 0). LDS reads/block-K-tile: 96 -> 64 wave-ops.
// Geometry = R6 (best measured): BM=256 BN=128 BK=128, 256 thr, 4 waves
// stacked on m, wave 64x128, acc 2x4 of 32x32x32 i8.
// out[m,n] = (sum_k A*W + sum_input[m]*zp_w[n]) * si[m]*sw[n] + bias[n]

#define BM 256
#define BN 128
#define BK 128

typedef __attribute__((ext_vector_type(4))) int int32x4;
typedef __attribute__((ext_vector_type(16))) int int32x16;

__device__ __forceinline__ void async_copy16(const uint8_t* g, uint8_t* l) {
  __builtin_amdgcn_global_load_lds(
      (const __attribute__((address_space(1))) uint32_t*)(const void*)g,
      (__attribute__((address_space(3))) uint32_t*)l,
      16, 0, 0);
}

// Pack v2, grid-stride. B -> linear packed rows (unchanged). A -> fragment
// panel order: for row r, col k (int8): p=r>>5, m32=r&31, c=k>>5,
// half=(k>>4)&1, slot=(k>>2)&3; u32 dst = (((p*(K/32)+c)*2+half)*32+m32)*4
// + slot. GEMM reads 16B at ((P*(K/32)+C)*64 + lane)*16, lane=half*32+m32
// (round-trip verified). Scattered 16-B write groups merge in L2.
__global__ __launch_bounds__(256) void pack_kernel(
    const int* __restrict__ A, const int* __restrict__ B,
    uint8_t* __restrict__ A8, uint8_t* __restrict__ B8,
    int nA4, int nTot4, int kc32, int shift /* log2(K/4) */) {
  const int stride = gridDim.x * blockDim.x;
  const int k4mask = (1 << shift) - 1;
  for (int t = blockIdx.x * blockDim.x + threadIdx.x; t < nTot4; t += stride) {
    const int32x4* src = (t < nA4) ? ((const int32x4*)A + t)
                                   : ((const int32x4*)B + (t - nA4));
    int32x4 x = __builtin_nontemporal_load(src);
    uint32_t v = (uint32_t)(x.x & 255) | ((uint32_t)(x.y & 255) << 8) |
                 ((uint32_t)(x.z & 255) << 16) | ((uint32_t)(x.w & 255) << 24);
    if (t < nA4) {
      const int r = t >> shift, k = (t & k4mask) << 2;
      const int p = r >> 5, m32 = r & 31;
      const int c = k >> 5, half = (k >> 4) & 1, slot = (k >> 2) & 3;
      ((uint32_t*)A8)[(size_t)(((p * kc32 + c) * 2 + half) * 32 + m32) * 4 + slot] = v;
    } else {
      ((uint32_t*)B8)[t - nA4] = v;
    }
  }
}

// Stage one 128x128 B tile into LDS (verbatim R6 B-path, conflicts 0).
// row_s = tid>>3 (0..31), slot cs = tid&7, global chunk cg = cs^((tid>>4)&7);
// issue p covers rows [p*32, p*32+32). Row r slot cs holds chunk cs^((r>>1)&7).
__device__ __forceinline__ void stage_B(const uint8_t* Bb, size_t sK, int k0,
                                        uint8_t* BsBuf, int ldst) {
#pragma unroll
  for (int p = 0; p < 4; ++p)
    async_copy16(Bb + (size_t)(p * 32) * sK + k0, BsBuf + p * 4096 + ldst);
}

__global__ __launch_bounds__(256, 2) void w8a8_gemm(
    const uint8_t* __restrict__ A8, const uint8_t* __restrict__ B8,
    const float* __restrict__ bias,
    const float* __restrict__ s_in,
    const float* __restrict__ s_w,
    const float* __restrict__ sum_in,
    const int* __restrict__ zp_w,
    float* __restrict__ out,
    int M, int N, int K) {
  __shared__ uint8_t Bs[BN * BK];  // 16 KiB only

  const int tid = threadIdx.x;
  const int bm = blockIdx.y, bn = blockIdx.x;
  const int row0 = bm * BM, col0 = bn * BN;

  const int wave = tid >> 6, lane = tid & 63;
  const int m32 = lane & 31, half = lane >> 5;
  const int wm = wave * 64;  // 4 waves stacked on m; wave spans all BN
  const size_t sK = (size_t)K;
  const int kc32 = K >> 5;

  // B staging geometry (see stage_B comment)
  const int cg = (tid & 7) ^ ((tid >> 4) & 7);
  const int row_s = tid >> 3;
  const int ldst = tid * 16;
  const uint8_t* Bb = B8 + (size_t)(col0 + row_s) * sK + cg * 16;

  // A fragment-panel bases: P_i = row0/32 + wave*2 + i
  size_t paOff[2];
#pragma unroll
  for (int i = 0; i < 2; ++i)
    paOff[i] = ((size_t)((row0 >> 5) + wave * 2 + i) * kc32) << 10;  // *1024
  const uint8_t* Apl = A8 + (lane << 4);

  int32x16 acc[2][4] = {};

  const int swzr = (m32 >> 1) & 7;
  const int NT = K / BK;
  for (int kt = 0; kt < NT; ++kt) {
    const int k0 = kt * BK;
    stage_B(Bb, sK, k0, Bs, ldst);  // 4 DMA issues (vmcnt)
    // A burst: 8 coalesced dwordx4 (L2/L3); latency rides under DMA drain.
    int32x4 afr[4][2];
    const size_t kcOff = ((size_t)(k0 >> 5)) << 10;
#pragma unroll
    for (int ks = 0; ks < 4; ++ks)
#pragma unroll
      for (int i = 0; i < 2; ++i)
        afr[ks][i] = *(const int32x4*)(Apl + paOff[i] + kcOff + ((size_t)ks << 10));
    __syncthreads();  // drains DMA + A loads; Bs ready

#pragma unroll
    for (int ks = 0; ks < 4; ++ks) {
      const int gran = ((ks * 2 + half) ^ swzr) * 16;
      int32x4 bfrag[4];
#pragma unroll
      for (int j = 0; j < 4; ++j)
        bfrag[j] = *(const int32x4*)&Bs[(j * 32 + m32) * BK + gran];
#pragma unroll
      for (int i = 0; i < 2; ++i)
#pragma unroll
        for (int j = 0; j < 4; ++j)
          acc[i][j] = __builtin_amdgcn_mfma_i32_32x32x32_i8(
              afr[ks][i], bfrag[j], acc[i][j], 0, 0, 0);
    }
    __syncthreads();  // protect Bs from next stage
  }

  // Epilogue: 32x32 C/D layout col=lane&31, row=(reg&3)+8*(reg>>2)+4*(lane>>5).
  float swj[4], zpj[4], bj[4];
#pragma unroll
  for (int j = 0; j < 4; ++j) {
    int gc = col0 + j * 32 + m32;
    swj[j] = s_w[gc];
    zpj[j] = (float)zp_w[gc];
    bj[j] = bias[gc];
  }
#pragma unroll
  for (int i = 0; i < 2; ++i) {
#pragma unroll
    for (int reg = 0; reg < 16; ++reg) {
      int gr = row0 + wm + i * 32 + (reg & 3) + 8 * (reg >> 2) + 4 * half;
      float siv = s_in[gr];
      float suv = sum_in[gr];
      float* orow = out + (size_t)gr * N + col0 + m32;
#pragma unroll
      for (int j = 0; j < 4; ++j) {
        float v = ((float)acc[i][j][reg] + suv * zpj[j]) * (siv * swj[j]) + bj[j];
        __builtin_nontemporal_store(v, &orow[j * 32]);
      }
    }
  }
}

// Fallback (ws too small / non-pow2 K): unpacked int32, BK=64, VALU pack.
__global__ __launch_bounds__(256) void w8a8_gemm_fallback(
    const int* __restrict__ A32, const int* __restrict__ B32,
    const float* __restrict__ bias,
    const float* __restrict__ s_in,
    const float* __restrict__ s_w,
    const float* __restrict__ sum_in,
    const int* __restrict__ zp_w,
    float* __restrict__ out,
    int M, int N, int K) {
  __shared__ uint8_t As[128 * 64];
  __shared__ uint8_t Bs[128 * 64];
  const int tid = threadIdx.x;
  const int bm = blockIdx.y, bn = blockIdx.x;
  const int row0 = bm * 128, col0 = bn * 128;
  const int wave = tid >> 6, lane = tid & 63;
  const int quad = lane >> 4, r = lane & 15;
  const int wm = (wave >> 1) * 64, wn = (wave & 1) * 64;
  const int lin = tid * 16;
  const int srow = lin >> 6;
  const int scol = lin & 63;
  const size_t sK = (size_t)K;
  int32x4 acc[4][4] = {};
  for (int k0 = 0; k0 < K; k0 += 64) {
#pragma unroll
    for (int c = 0; c < 2; ++c) {
      const int* ag = A32 + (size_t)(row0 + srow + c * 64) * sK + k0 + scol;
      const int* bg = B32 + (size_t)(col0 + srow + c * 64) * sK + k0 + scol;
      int32x4 pa, pb;
#pragma unroll
      for (int q = 0; q < 4; ++q) {
        int4 va = ((const int4*)ag)[q];
        int4 vb = ((const int4*)bg)[q];
        pa[q] = (int)((uint32_t)(va.x & 255) | ((uint32_t)(va.y & 255) << 8) |
                      ((uint32_t)(va.z & 255) << 16) | ((uint32_t)(va.w & 255) << 24));
        pb[q] = (int)((uint32_t)(vb.x & 255) | ((uint32_t)(vb.y & 255) << 8) |
                      ((uint32_t)(vb.z & 255) << 16) | ((uint32_t)(vb.w & 255) << 24));
      }
      *(int32x4*)&As[lin + c * 4096] = pa;
      *(int32x4*)&Bs[lin + c * 4096] = pb;
    }
    __syncthreads();
    int32x4 afrag[4], bfrag[4];
#pragma unroll
    for (int i = 0; i < 4; ++i)
      afrag[i] = *(const int32x4*)&As[(wm + i * 16 + r) * 64 + quad * 16];
#pragma unroll
    for (int j = 0; j < 4; ++j)
      bfrag[j] = *(const int32x4*)&Bs[(wn + j * 16 + r) * 64 + quad * 16];
#pragma unroll
    for (int i = 0; i < 4; ++i)
#pragma unroll
      for (int j = 0; j < 4; ++j)
        acc[i][j] = __builtin_amdgcn_mfma_i32_16x16x64_i8(afrag[i], bfrag[j],
                                                          acc[i][j], 0, 0, 0);
    __syncthreads();
  }
  float swj[4], zpj[4], bj[4];
#pragma unroll
  for (int j = 0; j < 4; ++j) {
    int gc = col0 + wn + j * 16 + r;
    swj[j] = s_w[gc];
    zpj[j] = (float)zp_w[gc];
    bj[j] = bias[gc];
  }
#pragma unroll
  for (int i = 0; i < 4; ++i) {
#pragma unroll
    for (int t = 0; t < 4; ++t) {
      int gr = row0 + wm + i * 16 + quad * 4 + t;
      float siv = s_in[gr];
      float suv = sum_in[gr];
      float* orow = out + (size_t)gr * N + col0 + wn + r;
#pragma unroll
      for (int j = 0; j < 4; ++j) {
        float v = ((float)acc[i][j][t] + suv * zpj[j]) * (siv * swj[j]) + bj[j];
        orow[j * 16] = v;
      }
    }
  }
}

extern "C" void kernel_launch(void* const* d_in, const int* in_sizes, int n_in,
                              void* d_out, int out_size, void* d_ws, size_t ws_size,
                              hipStream_t stream) {
  const int* x_q = (const int*)d_in[0];
  const int* w_q = (const int*)d_in[1];
  const float* bias = (const float*)d_in[2];
  const float* s_in = (const float*)d_in[3];
  const float* s_w = (const float*)d_in[4];
  const float* sum_in = (const float*)d_in[5];
  const int* zp_w = (const int*)d_in[6];
  float* out = (float*)d_out;

  const int M = in_sizes[3];
  const int N = in_sizes[2];
  const int K = in_sizes[0] / M;

  const size_t needA = (size_t)M * K;
  const size_t needB = (size_t)N * K;
  const bool kPow2 = (K & (K - 1)) == 0;

  if (ws_size >= needA + needB && (M % BM) == 0 && (N % BN) == 0 &&
      (K % BK) == 0 && kPow2) {
    uint8_t* A8 = (uint8_t*)d_ws;
    uint8_t* B8 = A8 + needA;
    const int nA4 = (int)(needA / 4);
    const int nTot4 = (int)((needA + needB) / 4);
    int shift = 0;
    while ((1 << (shift + 1)) <= (K >> 2)) ++shift;  // log2(K/4)
    int nblk = (nTot4 + 255) / 256;
    if (nblk > 2048) nblk = 2048;
    pack_kernel<<<nblk, 256, 0, stream>>>(x_q, w_q, A8, B8, nA4, nTot4,
                                          K >> 5, shift);
    dim3 grid(N / BN, M / BM), block(256);
    w8a8_gemm<<<grid, block, 0, stream>>>(A8, B8, bias, s_in, s_w, sum_in,
                                          zp_w, out, M, N, K);
  } else {
    dim3 grid(N / 128, M / 128), block(256);
    w8a8_gemm_fallback<<<grid, block, 0, stream>>>(x_q, w_q, bias, s_in, s_w,
                                                   sum_in, zp_w, out, M, N, K);
  }
}